// Round 2
// baseline (954.038 us; speedup 1.0000x reference)
//
#include <hip/hip_runtime.h>
#include <hip/hip_bf16.h>
#include <math.h>

// Problem constants (from reference setup_inputs)
constexpr int N  = 4;
constexpr int C  = 64;
constexpr int H  = 96;    // low-res
constexpr int W  = 192;
constexpr int R  = 4;     // upsample rate
constexpr int Hf = H * R; // 384
constexpr int Wf = W * R; // 768

__global__ __launch_bounds__(256)
void fused_upsample_warp(const float* __restrict__ x,
                         const float* __restrict__ flow,
                         const float* __restrict__ mask,
                         float* __restrict__ out) {
    int idx = blockIdx.x * blockDim.x + threadIdx.x;
    const int total = N * Hf * Wf;
    if (idx >= total) return;

    const int xpix = idx % Wf;
    int t = idx / Wf;
    const int ypix = t % Hf;
    const int n = t / Hf;

    const int w  = xpix >> 2, rj = xpix & 3;
    const int h  = ypix >> 2, ri = ypix & 3;

    const int HW = H * W;

    // ---- softmax over the 9 mask logits for this (ri,rj,h,w) ----
    // mask layout: [N][9*16][H][W], channel = k*16 + ri*4 + rj
    const float* mbase = mask + ((size_t)n * 144 + (size_t)(ri * 4 + rj)) * HW
                              + (size_t)h * W + w;
    float mv[9];
    float mx = -INFINITY;
#pragma unroll
    for (int k = 0; k < 9; ++k) {
        mv[k] = mbase[(size_t)k * 16 * HW];
        mx = fmaxf(mx, mv[k]);
    }
    float s = 0.f;
#pragma unroll
    for (int k = 0; k < 9; ++k) {
        mv[k] = __expf(mv[k] - mx);
        s += mv[k];
    }
    const float inv = 1.0f / s;

    // ---- convex combination of 3x3 low-res flow neighborhood ----
    const float* f0 = flow + (size_t)n * 2 * HW;  // comp0 plane; comp1 at +HW
    float fx = 0.f, fy = 0.f;
#pragma unroll
    for (int k = 0; k < 9; ++k) {
        const int di = k / 3 - 1;
        const int dj = k % 3 - 1;
        const int hh = h + di, ww = w + dj;
        float vx = 0.f, vy = 0.f;
        if (hh >= 0 && hh < H && ww >= 0 && ww < W) {
            const int o = hh * W + ww;
            vx = f0[o];
            vy = f0[HW + o];
        }
        const float wk = mv[k] * inv;
        fx += wk * vx;
        fy += wk * vy;
    }
    fx *= (float)R;   // f = rate * flow (linear, applied after combination)
    fy *= (float)R;

    // ---- bilinear warp, zeros padding, pixel-space coords ----
    const float sx = (float)xpix + fx;
    const float sy = (float)ypix + fy;
    const float x0f = floorf(sx), y0f = floorf(sy);
    const int x0 = (int)x0f, y0 = (int)y0f;
    const int x1 = x0 + 1,  y1 = y0 + 1;
    const float wx1 = sx - x0f, wx0 = 1.f - wx1;
    const float wy1 = sy - y0f, wy0 = 1.f - wy1;

    const bool vx0 = (x0 >= 0) & (x0 < Wf);
    const bool vx1 = (x1 >= 0) & (x1 < Wf);
    const bool vy0 = (y0 >= 0) & (y0 < Hf);
    const bool vy1 = (y1 >= 0) & (y1 < Hf);

    const int x0c = min(max(x0, 0), Wf - 1), x1c = min(max(x1, 0), Wf - 1);
    const int y0c = min(max(y0, 0), Hf - 1), y1c = min(max(y1, 0), Hf - 1);

    const float w00 = wx0 * wy0 * (float)(vx0 & vy0);
    const float w10 = wx1 * wy0 * (float)(vx1 & vy0);
    const float w01 = wx0 * wy1 * (float)(vx0 & vy1);
    const float w11 = wx1 * wy1 * (float)(vx1 & vy1);

    const size_t HWf = (size_t)Hf * Wf;
    const float* xb = x + (size_t)n * C * HWf;
    const size_t i00 = (size_t)y0c * Wf + x0c;
    const size_t i10 = (size_t)y0c * Wf + x1c;
    const size_t i01 = (size_t)y1c * Wf + x0c;
    const size_t i11 = (size_t)y1c * Wf + x1c;

    float* ob = out + (size_t)n * C * HWf + (size_t)ypix * Wf + xpix;

#pragma unroll 4
    for (int c = 0; c < C; ++c) {
        const float* xc = xb + (size_t)c * HWf;
        const float v = w00 * xc[i00] + w10 * xc[i10]
                      + w01 * xc[i01] + w11 * xc[i11];
        __builtin_nontemporal_store(v, ob + (size_t)c * HWf);
    }
}

extern "C" void kernel_launch(void* const* d_in, const int* in_sizes, int n_in,
                              void* d_out, int out_size, void* d_ws, size_t ws_size,
                              hipStream_t stream) {
    const float* x    = (const float*)d_in[0];
    const float* flow = (const float*)d_in[1];
    const float* mask = (const float*)d_in[2];
    float* out = (float*)d_out;

    const int total = N * Hf * Wf;           // 1,179,648
    const int block = 256;
    const int grid = (total + block - 1) / block;  // 4608
    fused_upsample_warp<<<grid, block, 0, stream>>>(x, flow, mask, out);
}

// Round 3
// 764.146 us; speedup vs baseline: 1.2485x; 1.2485x over previous
//
#include <hip/hip_runtime.h>
#include <hip/hip_bf16.h>
#include <math.h>

// Problem constants (from reference setup_inputs)
constexpr int N  = 4;
constexpr int C  = 64;
constexpr int H  = 96;    // low-res
constexpr int W  = 192;
constexpr int R  = 4;     // upsample rate
constexpr int Hf = H * R; // 384
constexpr int Wf = W * R; // 768
constexpr int HW  = H * W;        // 18432
constexpr int HWf = Hf * Wf;      // 294912
constexpr size_t XT_BYTES = (size_t)N * HWf * C * sizeof(__hip_bfloat16); // ~151 MB

__device__ __forceinline__ float bf2f(unsigned short u) {
    unsigned v = ((unsigned)u) << 16;
    float f;
    __builtin_memcpy(&f, &v, 4);
    return f;
}

// ---------------- Phase 1: x [N][C][Hf][Wf] f32  ->  xT [N][Hf*Wf][C] bf16 ----
__global__ __launch_bounds__(256)
void transpose_to_bf16(const float* __restrict__ x, __hip_bfloat16* __restrict__ xT) {
    __shared__ float tile[64][65];   // [pixel][channel], +1 pad
    const int b = blockIdx.x;
    const int tilesPerN = HWf / 64;  // 4608
    const int n = b / tilesPerN;
    const int pixbase = (b % tilesPerN) * 64;
    const int tid = threadIdx.x;

    // read: 64 channels x 64 pixels, coalesced along pixels
    const int px = tid & 63;
    const int c0 = tid >> 6;         // 0..3
    const float* xb = x + (size_t)n * C * HWf + pixbase;
#pragma unroll
    for (int i = 0; i < 16; ++i) {
        const int c = i * 4 + c0;
        tile[px][c] = xb[(size_t)c * HWf + px];
    }
    __syncthreads();

    // write: each thread emits 16 channels (32B) of one pixel, contiguous
    const int wpx = tid >> 2;
    const int cc  = (tid & 3) * 16;
    alignas(16) __hip_bfloat16 h[16];
#pragma unroll
    for (int j = 0; j < 16; ++j)
        h[j] = __float2bfloat16(tile[wpx][cc + j]);

    uint4* dst = (uint4*)(xT + ((size_t)(n * HWf + pixbase + wpx)) * C + cc);
    const uint4* src = (const uint4*)h;
    dst[0] = src[0];
    dst[1] = src[1];
}

// ---------------- Phase 2: fused upsample + warp, gathering channels-last bf16
__global__ __launch_bounds__(256)
void fused_gather_bf16(const __hip_bfloat16* __restrict__ xT,
                       const float* __restrict__ flow,
                       const float* __restrict__ mask,
                       float* __restrict__ out) {
    int idx = blockIdx.x * blockDim.x + threadIdx.x;
    const int total = N * Hf * Wf;
    if (idx >= total) return;

    const int xpix = idx % Wf;
    int t = idx / Wf;
    const int ypix = t % Hf;
    const int n = t / Hf;

    const int w  = xpix >> 2, rj = xpix & 3;
    const int h  = ypix >> 2, ri = ypix & 3;

    // softmax over 9 mask logits; channel = k*16 + ri*4 + rj
    const float* mbase = mask + ((size_t)n * 144 + (size_t)(ri * 4 + rj)) * HW
                              + (size_t)h * W + w;
    float mv[9];
    float mx = -INFINITY;
#pragma unroll
    for (int k = 0; k < 9; ++k) {
        mv[k] = mbase[(size_t)k * 16 * HW];
        mx = fmaxf(mx, mv[k]);
    }
    float s = 0.f;
#pragma unroll
    for (int k = 0; k < 9; ++k) {
        mv[k] = __expf(mv[k] - mx);
        s += mv[k];
    }
    const float inv = 1.0f / s;

    // convex combination of 3x3 low-res flow neighborhood
    const float* f0 = flow + (size_t)n * 2 * HW;
    float fx = 0.f, fy = 0.f;
#pragma unroll
    for (int k = 0; k < 9; ++k) {
        const int di = k / 3 - 1;
        const int dj = k % 3 - 1;
        const int hh = h + di, ww = w + dj;
        float vx = 0.f, vy = 0.f;
        if (hh >= 0 && hh < H && ww >= 0 && ww < W) {
            const int o = hh * W + ww;
            vx = f0[o];
            vy = f0[HW + o];
        }
        const float wk = mv[k] * inv;
        fx += wk * vx;
        fy += wk * vy;
    }
    fx *= (float)R;
    fy *= (float)R;

    // bilinear warp setup
    const float sx = (float)xpix + fx;
    const float sy = (float)ypix + fy;
    const float x0f = floorf(sx), y0f = floorf(sy);
    const int x0 = (int)x0f, y0 = (int)y0f;
    const int x1 = x0 + 1,  y1 = y0 + 1;
    const float wx1 = sx - x0f, wx0 = 1.f - wx1;
    const float wy1 = sy - y0f, wy0 = 1.f - wy1;

    const bool vx0 = (x0 >= 0) & (x0 < Wf);
    const bool vx1 = (x1 >= 0) & (x1 < Wf);
    const bool vy0 = (y0 >= 0) & (y0 < Hf);
    const bool vy1 = (y1 >= 0) & (y1 < Hf);

    const int x0c = min(max(x0, 0), Wf - 1), x1c = min(max(x1, 0), Wf - 1);
    const int y0c = min(max(y0, 0), Hf - 1), y1c = min(max(y1, 0), Hf - 1);

    const float w00 = wx0 * wy0 * (float)(vx0 & vy0);
    const float w10 = wx1 * wy0 * (float)(vx1 & vy0);
    const float w01 = wx0 * wy1 * (float)(vx0 & vy1);
    const float w11 = wx1 * wy1 * (float)(vx1 & vy1);

    const __hip_bfloat16* xb = xT + (size_t)n * HWf * C;
    const uint4* p00 = (const uint4*)(xb + (size_t)(y0c * Wf + x0c) * C);
    const uint4* p10 = (const uint4*)(xb + (size_t)(y0c * Wf + x1c) * C);
    const uint4* p01 = (const uint4*)(xb + (size_t)(y1c * Wf + x0c) * C);
    const uint4* p11 = (const uint4*)(xb + (size_t)(y1c * Wf + x1c) * C);

    float* ob = out + (size_t)n * C * HWf + (size_t)ypix * Wf + xpix;

#pragma unroll
    for (int k = 0; k < 8; ++k) {          // 8 channels per chunk (16B bf16)
        const uint4 a = p00[k];
        const uint4 b = p10[k];
        const uint4 c = p01[k];
        const uint4 d = p11[k];
        const unsigned short* ua = (const unsigned short*)&a;
        const unsigned short* ub = (const unsigned short*)&b;
        const unsigned short* uc = (const unsigned short*)&c;
        const unsigned short* ud = (const unsigned short*)&d;
#pragma unroll
        for (int j = 0; j < 8; ++j) {
            const float v = w00 * bf2f(ua[j]) + w10 * bf2f(ub[j])
                          + w01 * bf2f(uc[j]) + w11 * bf2f(ud[j]);
            __builtin_nontemporal_store(v, ob + (size_t)(8 * k + j) * HWf);
        }
    }
}

// ---------------- Fallback (round-2 kernel): direct planar f32 gather --------
__global__ __launch_bounds__(256)
void fused_upsample_warp(const float* __restrict__ x,
                         const float* __restrict__ flow,
                         const float* __restrict__ mask,
                         float* __restrict__ out) {
    int idx = blockIdx.x * blockDim.x + threadIdx.x;
    const int total = N * Hf * Wf;
    if (idx >= total) return;

    const int xpix = idx % Wf;
    int t = idx / Wf;
    const int ypix = t % Hf;
    const int n = t / Hf;

    const int w  = xpix >> 2, rj = xpix & 3;
    const int h  = ypix >> 2, ri = ypix & 3;

    const float* mbase = mask + ((size_t)n * 144 + (size_t)(ri * 4 + rj)) * HW
                              + (size_t)h * W + w;
    float mv[9];
    float mx = -INFINITY;
#pragma unroll
    for (int k = 0; k < 9; ++k) {
        mv[k] = mbase[(size_t)k * 16 * HW];
        mx = fmaxf(mx, mv[k]);
    }
    float s = 0.f;
#pragma unroll
    for (int k = 0; k < 9; ++k) {
        mv[k] = __expf(mv[k] - mx);
        s += mv[k];
    }
    const float inv = 1.0f / s;

    const float* f0 = flow + (size_t)n * 2 * HW;
    float fx = 0.f, fy = 0.f;
#pragma unroll
    for (int k = 0; k < 9; ++k) {
        const int di = k / 3 - 1;
        const int dj = k % 3 - 1;
        const int hh = h + di, ww = w + dj;
        float vx = 0.f, vy = 0.f;
        if (hh >= 0 && hh < H && ww >= 0 && ww < W) {
            const int o = hh * W + ww;
            vx = f0[o];
            vy = f0[HW + o];
        }
        const float wk = mv[k] * inv;
        fx += wk * vx;
        fy += wk * vy;
    }
    fx *= (float)R;
    fy *= (float)R;

    const float sx = (float)xpix + fx;
    const float sy = (float)ypix + fy;
    const float x0f = floorf(sx), y0f = floorf(sy);
    const int x0 = (int)x0f, y0 = (int)y0f;
    const int x1 = x0 + 1,  y1 = y0 + 1;
    const float wx1 = sx - x0f, wx0 = 1.f - wx1;
    const float wy1 = sy - y0f, wy0 = 1.f - wy1;

    const bool vx0 = (x0 >= 0) & (x0 < Wf);
    const bool vx1 = (x1 >= 0) & (x1 < Wf);
    const bool vy0 = (y0 >= 0) & (y0 < Hf);
    const bool vy1 = (y1 >= 0) & (y1 < Hf);

    const int x0c = min(max(x0, 0), Wf - 1), x1c = min(max(x1, 0), Wf - 1);
    const int y0c = min(max(y0, 0), Hf - 1), y1c = min(max(y1, 0), Hf - 1);

    const float w00 = wx0 * wy0 * (float)(vx0 & vy0);
    const float w10 = wx1 * wy0 * (float)(vx1 & vy0);
    const float w01 = wx0 * wy1 * (float)(vx0 & vy1);
    const float w11 = wx1 * wy1 * (float)(vx1 & vy1);

    const size_t HWfs = (size_t)HWf;
    const float* xb = x + (size_t)n * C * HWfs;
    const size_t i00 = (size_t)y0c * Wf + x0c;
    const size_t i10 = (size_t)y0c * Wf + x1c;
    const size_t i01 = (size_t)y1c * Wf + x0c;
    const size_t i11 = (size_t)y1c * Wf + x1c;

    float* ob = out + (size_t)n * C * HWfs + (size_t)ypix * Wf + xpix;

#pragma unroll 4
    for (int c = 0; c < C; ++c) {
        const float* xc = xb + (size_t)c * HWfs;
        const float v = w00 * xc[i00] + w10 * xc[i10]
                      + w01 * xc[i01] + w11 * xc[i11];
        __builtin_nontemporal_store(v, ob + (size_t)c * HWfs);
    }
}

extern "C" void kernel_launch(void* const* d_in, const int* in_sizes, int n_in,
                              void* d_out, int out_size, void* d_ws, size_t ws_size,
                              hipStream_t stream) {
    const float* x    = (const float*)d_in[0];
    const float* flow = (const float*)d_in[1];
    const float* mask = (const float*)d_in[2];
    float* out = (float*)d_out;

    const int total = N * Hf * Wf;                 // 1,179,648
    const int block = 256;
    const int grid2 = (total + block - 1) / block; // 4608

    if (ws_size >= XT_BYTES) {
        __hip_bfloat16* xT = (__hip_bfloat16*)d_ws;
        const int grid1 = N * (HWf / 64);          // 18432
        transpose_to_bf16<<<grid1, block, 0, stream>>>(x, xT);
        fused_gather_bf16<<<grid2, block, 0, stream>>>(xT, flow, mask, out);
    } else {
        fused_upsample_warp<<<grid2, block, 0, stream>>>(x, flow, mask, out);
    }
}

// Round 4
// 705.528 us; speedup vs baseline: 1.3522x; 1.0831x over previous
//
#include <hip/hip_runtime.h>
#include <hip/hip_fp16.h>
#include <math.h>

// Problem constants (from reference setup_inputs)
constexpr int N  = 4;
constexpr int C  = 64;
constexpr int H  = 96;    // low-res
constexpr int W  = 192;
constexpr int R  = 4;     // upsample rate
constexpr int Hf = H * R; // 384
constexpr int Wf = W * R; // 768
constexpr int HW  = H * W;        // 18432
constexpr int HWf = Hf * Wf;      // 294912
constexpr size_t XT_BYTES = (size_t)N * HWf * C * sizeof(__half); // ~151 MB

// Gather grid geometry: 4x64 output tiles
constexpr int BANDS   = Hf / 4;          // 96 bands (1 band = 1 low-res row)
constexpr int TCOLS   = Wf / 64;         // 12 tiles per band
constexpr int BLK_IMG = BANDS * TCOLS;   // 1152 blocks per image
constexpr int NBLK    = N * BLK_IMG;     // 4608 total (divisible by 8)

// ---------------- Phase 1: x [N][C][Hf][Wf] f32  ->  xT [N][Hf*Wf][C] f16 ----
__global__ __launch_bounds__(256)
void transpose_to_f16(const float* __restrict__ x, __half* __restrict__ xT) {
    __shared__ float tile[64][65];   // [pixel][channel], +1 pad
    const int b = blockIdx.x;
    const int tilesPerN = HWf / 64;  // 4608
    const int n = b / tilesPerN;
    const int pixbase = (b % tilesPerN) * 64;
    const int tid = threadIdx.x;

    // read: float4 along pixels — 16B/lane, 1KB per wave instruction
    const float* xb = x + (size_t)n * C * HWf + pixbase;
    const int cg  = tid >> 4;        // 0..15
    const int px4 = (tid & 15) * 4;  // 0,4,..,60
#pragma unroll
    for (int i = 0; i < 4; ++i) {
        const int c = i * 16 + cg;
        const float4 v = *(const float4*)(xb + (size_t)c * HWf + px4);
        tile[px4 + 0][c] = v.x;
        tile[px4 + 1][c] = v.y;
        tile[px4 + 2][c] = v.z;
        tile[px4 + 3][c] = v.w;
    }
    __syncthreads();

    // write: each thread emits 16 channels (32B) of one pixel, contiguous
    const int wpx = tid >> 2;
    const int c0  = (tid & 3) * 16;
    alignas(16) __half h[16];
#pragma unroll
    for (int j = 0; j < 16; ++j)
        h[j] = __float2half(tile[wpx][c0 + j]);

    uint4* dst = (uint4*)(xT + ((size_t)(n * HWf + pixbase + wpx)) * C + c0);
    const uint4* src = (const uint4*)h;
    dst[0] = src[0];
    dst[1] = src[1];
}

// ---------------- Phase 2: fused upsample + warp, channels-last f16 gather ---
// 4x64 tiles, XCD-chunked swizzle: each XCD sweeps a contiguous 192-row slab,
// so the flow-scatter window (~±24 rows ≈ 4.7MB of xT) stays L2-resident.
__global__ __launch_bounds__(256)
void fused_gather_f16(const __half* __restrict__ xT,
                      const float* __restrict__ flow,
                      const float* __restrict__ mask,
                      float* __restrict__ out) {
    const int bid = blockIdx.x;
    // bijective: XCD k (= bid%8) gets logical blocks [k*576, (k+1)*576)
    const int l = (bid & 7) * (NBLK / 8) + (bid >> 3);
    const int n = l / BLK_IMG;
    const int rem = l - n * BLK_IMG;
    const int band = rem / TCOLS;        // 0..95  (== low-res row h)
    const int tcol = rem - band * TCOLS;

    const int ty = threadIdx.x >> 6;     // 0..3  (== ri)
    const int tx = threadIdx.x & 63;
    const int ypix = band * 4 + ty;
    const int xpix = tcol * 64 + tx;

    const int w  = xpix >> 2, rj = xpix & 3;
    const int h  = band;                 // ypix>>2
    const int ri = ty;                   // ypix&3

    // softmax over 9 mask logits; channel = k*16 + ri*4 + rj  (read-once: nt)
    const float* mbase = mask + ((size_t)n * 144 + (size_t)(ri * 4 + rj)) * HW
                              + (size_t)h * W + w;
    float mv[9];
    float mx = -INFINITY;
#pragma unroll
    for (int k = 0; k < 9; ++k) {
        mv[k] = __builtin_nontemporal_load(mbase + (size_t)k * 16 * HW);
        mx = fmaxf(mx, mv[k]);
    }
    float s = 0.f;
#pragma unroll
    for (int k = 0; k < 9; ++k) {
        mv[k] = __expf(mv[k] - mx);
        s += mv[k];
    }
    const float inv = 1.0f / s;

    // convex combination of 3x3 low-res flow neighborhood
    const float* f0 = flow + (size_t)n * 2 * HW;
    float fx = 0.f, fy = 0.f;
#pragma unroll
    for (int k = 0; k < 9; ++k) {
        const int di = k / 3 - 1;
        const int dj = k % 3 - 1;
        const int hh = h + di, ww = w + dj;
        float vx = 0.f, vy = 0.f;
        if (hh >= 0 && hh < H && ww >= 0 && ww < W) {
            const int o = hh * W + ww;
            vx = f0[o];
            vy = f0[HW + o];
        }
        const float wk = mv[k] * inv;
        fx += wk * vx;
        fy += wk * vy;
    }
    fx *= (float)R;
    fy *= (float)R;

    // bilinear warp setup
    const float sx = (float)xpix + fx;
    const float sy = (float)ypix + fy;
    const float x0f = floorf(sx), y0f = floorf(sy);
    const int x0 = (int)x0f, y0 = (int)y0f;
    const int x1 = x0 + 1,  y1 = y0 + 1;
    const float wx1 = sx - x0f, wx0 = 1.f - wx1;
    const float wy1 = sy - y0f, wy0 = 1.f - wy1;

    const bool vx0 = (x0 >= 0) & (x0 < Wf);
    const bool vx1 = (x1 >= 0) & (x1 < Wf);
    const bool vy0 = (y0 >= 0) & (y0 < Hf);
    const bool vy1 = (y1 >= 0) & (y1 < Hf);

    const int x0c = min(max(x0, 0), Wf - 1), x1c = min(max(x1, 0), Wf - 1);
    const int y0c = min(max(y0, 0), Hf - 1), y1c = min(max(y1, 0), Hf - 1);

    const float w00 = wx0 * wy0 * (float)(vx0 & vy0);
    const float w10 = wx1 * wy0 * (float)(vx1 & vy0);
    const float w01 = wx0 * wy1 * (float)(vx0 & vy1);
    const float w11 = wx1 * wy1 * (float)(vx1 & vy1);

    const __half* xb = xT + (size_t)n * HWf * C;
    const uint4* p00 = (const uint4*)(xb + (size_t)(y0c * Wf + x0c) * C);
    const uint4* p10 = (const uint4*)(xb + (size_t)(y0c * Wf + x1c) * C);
    const uint4* p01 = (const uint4*)(xb + (size_t)(y1c * Wf + x0c) * C);
    const uint4* p11 = (const uint4*)(xb + (size_t)(y1c * Wf + x1c) * C);

    float* ob = out + (size_t)n * C * HWf + (size_t)ypix * Wf + xpix;

#pragma unroll
    for (int k = 0; k < 8; ++k) {          // 8 channels per 16B f16 chunk
        const uint4 a = p00[k];
        const uint4 b = p10[k];
        const uint4 c = p01[k];
        const uint4 d = p11[k];
        const __half* ha = (const __half*)&a;
        const __half* hb = (const __half*)&b;
        const __half* hc = (const __half*)&c;
        const __half* hd = (const __half*)&d;
#pragma unroll
        for (int j = 0; j < 8; ++j) {
            const float v = w00 * __half2float(ha[j]) + w10 * __half2float(hb[j])
                          + w01 * __half2float(hc[j]) + w11 * __half2float(hd[j]);
            __builtin_nontemporal_store(v, ob + (size_t)(8 * k + j) * HWf);
        }
    }
}

// ---------------- Fallback: direct planar f32 gather (round-2 kernel) -------
__global__ __launch_bounds__(256)
void fused_upsample_warp(const float* __restrict__ x,
                         const float* __restrict__ flow,
                         const float* __restrict__ mask,
                         float* __restrict__ out) {
    int idx = blockIdx.x * blockDim.x + threadIdx.x;
    const int total = N * Hf * Wf;
    if (idx >= total) return;

    const int xpix = idx % Wf;
    int t = idx / Wf;
    const int ypix = t % Hf;
    const int n = t / Hf;

    const int w  = xpix >> 2, rj = xpix & 3;
    const int h  = ypix >> 2, ri = ypix & 3;

    const float* mbase = mask + ((size_t)n * 144 + (size_t)(ri * 4 + rj)) * HW
                              + (size_t)h * W + w;
    float mv[9];
    float mx = -INFINITY;
#pragma unroll
    for (int k = 0; k < 9; ++k) {
        mv[k] = mbase[(size_t)k * 16 * HW];
        mx = fmaxf(mx, mv[k]);
    }
    float s = 0.f;
#pragma unroll
    for (int k = 0; k < 9; ++k) {
        mv[k] = __expf(mv[k] - mx);
        s += mv[k];
    }
    const float inv = 1.0f / s;

    const float* f0 = flow + (size_t)n * 2 * HW;
    float fx = 0.f, fy = 0.f;
#pragma unroll
    for (int k = 0; k < 9; ++k) {
        const int di = k / 3 - 1;
        const int dj = k % 3 - 1;
        const int hh = h + di, ww = w + dj;
        float vx = 0.f, vy = 0.f;
        if (hh >= 0 && hh < H && ww >= 0 && ww < W) {
            const int o = hh * W + ww;
            vx = f0[o];
            vy = f0[HW + o];
        }
        const float wk = mv[k] * inv;
        fx += wk * vx;
        fy += wk * vy;
    }
    fx *= (float)R;
    fy *= (float)R;

    const float sx = (float)xpix + fx;
    const float sy = (float)ypix + fy;
    const float x0f = floorf(sx), y0f = floorf(sy);
    const int x0 = (int)x0f, y0 = (int)y0f;
    const int x1 = x0 + 1,  y1 = y0 + 1;
    const float wx1 = sx - x0f, wx0 = 1.f - wx1;
    const float wy1 = sy - y0f, wy0 = 1.f - wy1;

    const bool vx0 = (x0 >= 0) & (x0 < Wf);
    const bool vx1 = (x1 >= 0) & (x1 < Wf);
    const bool vy0 = (y0 >= 0) & (y0 < Hf);
    const bool vy1 = (y1 >= 0) & (y1 < Hf);

    const int x0c = min(max(x0, 0), Wf - 1), x1c = min(max(x1, 0), Wf - 1);
    const int y0c = min(max(y0, 0), Hf - 1), y1c = min(max(y1, 0), Hf - 1);

    const float w00 = wx0 * wy0 * (float)(vx0 & vy0);
    const float w10 = wx1 * wy0 * (float)(vx1 & vy0);
    const float w01 = wx0 * wy1 * (float)(vx0 & vy1);
    const float w11 = wx1 * wy1 * (float)(vx1 & vy1);

    const size_t HWfs = (size_t)HWf;
    const float* xb = x + (size_t)n * C * HWfs;
    const size_t i00 = (size_t)y0c * Wf + x0c;
    const size_t i10 = (size_t)y0c * Wf + x1c;
    const size_t i01 = (size_t)y1c * Wf + x0c;
    const size_t i11 = (size_t)y1c * Wf + x1c;

    float* ob = out + (size_t)n * C * HWfs + (size_t)ypix * Wf + xpix;

#pragma unroll 4
    for (int c = 0; c < C; ++c) {
        const float* xc = xb + (size_t)c * HWfs;
        const float v = w00 * xc[i00] + w10 * xc[i10]
                      + w01 * xc[i01] + w11 * xc[i11];
        __builtin_nontemporal_store(v, ob + (size_t)c * HWfs);
    }
}

extern "C" void kernel_launch(void* const* d_in, const int* in_sizes, int n_in,
                              void* d_out, int out_size, void* d_ws, size_t ws_size,
                              hipStream_t stream) {
    const float* x    = (const float*)d_in[0];
    const float* flow = (const float*)d_in[1];
    const float* mask = (const float*)d_in[2];
    float* out = (float*)d_out;

    const int block = 256;

    if (ws_size >= XT_BYTES) {
        __half* xT = (__half*)d_ws;
        const int grid1 = N * (HWf / 64);          // 18432
        transpose_to_f16<<<grid1, block, 0, stream>>>(x, xT);
        fused_gather_f16<<<NBLK, block, 0, stream>>>(xT, flow, mask, out);
    } else {
        const int total = N * Hf * Wf;
        const int grid2 = (total + block - 1) / block;
        fused_upsample_warp<<<grid2, block, 0, stream>>>(x, flow, mask, out);
    }
}